// Round 1
// baseline (416.394 us; speedup 1.0000x reference)
//
#include <hip/hip_runtime.h>
#include <math.h>

#define BATCH 8
#define NPT   2048
#define DIM   32
#define RPB   32                      // rows per block: 2 strips of 16
#define CPW   (NPT / 4)               // 512 cols per wave
#define NT    (CPW / 16)              // 32 col-tiles of 16 per wave
#define NBLK  (NPT / RPB)             // 64 row blocks
#define L2E   1.44269504088896f
#define BN    (BATCH * NPT)

typedef __attribute__((ext_vector_type(8))) _Float16 half8;
typedef __attribute__((ext_vector_type(4))) float floatx4;
typedef unsigned short u16;
typedef unsigned int u32;

__device__ __forceinline__ u16 f2h_bits(float v) {
    _Float16 h = (_Float16)v;
    return *(u16*)&h;
}
__device__ __forceinline__ float exp2v(float x) { return __builtin_amdgcn_exp2f(x); }

struct SymSet {
    const u16* Ah;        // row-side plain fp16 [BATCH][NPT][DIM]
    const u16* Bh;        // col-side log2e-scaled fp16
    const float* tls;     // log2e*(pot+cw) on cols
    const float* qX;      // 0.5*||row||^2
    const float* bmIn;    // [BATCH][128] per-16 max of (pot+cw) on cols
    const float* cwNext;
    const float* prev;
    float* out;
    float* tlsOut;
    float* bmOut;
};
struct FusedSet {
    const u16* Xh;        // rows X plain fp16
    const u16* Ysh;       // cols Y log2e-scaled fp16
    const float* tlsG;    // log2e*(g+c_y) per col  (f-side weights)
    const float* tlsF;    // log2e*(f+c_x) per row  (g-side weights)
    const float* qX;
    const float* bmG;     // -> TmaxG (normalizes f-side)
    const float* bmF;     // -> TmaxF (normalizes g-side)
    const float* c_x;
    const float* prevF;
    float* outF;
    float* tlsFOut;
    float* bmFOut;
    float* gpart;         // [BATCH][NBLK][NPT] weighted col partials
};
struct CtArgs { FusedSet fs; SymSet s[2]; int average; };

// blockIdx.y==0: fused pass over kxy producing f-row LSE AND g-col partials.
//   e = 2^(L2E*x.y); sumF += 2^(tg_k - L2E*TmaxG) * e;  gl += 2^(tf_l - L2E*TmaxF) * e.
// blockIdx.y==1,2: symmetric sets, bias folded into MFMA C-operand:
//   acc = L2E*x.y + (t_k - L2E*Tmax); sum += 2^acc  (identical terms, one rounding).
__global__ __launch_bounds__(256, 7) void ct2_kernel(CtArgs args) {
    const int batch = blockIdx.z;
    const int row0 = blockIdx.x * RPB;
    const int tid  = threadIdx.x;
    const int w = tid >> 6, lane = tid & 63, n = lane & 15, quad = lane >> 4;
    const int qk = quad * 8;
    const size_t pbase = (size_t)batch * NPT * DIM;
    const size_t vbase = (size_t)batch * NPT;

    __shared__ float lsum[RPB][4];

    if (blockIdx.y == 0) {
        // ---------------- fused cross pass ----------------
        const FusedSet fs = args.fs;
        const u16* __restrict__ Ah = fs.Xh + pbase;
        const u16* __restrict__ Bh = fs.Ysh + pbase;
        const float* __restrict__ tg = fs.tlsG + vbase;
        const float* __restrict__ tf = fs.tlsF + vbase;

        half8 ah[2];
        #pragma unroll
        for (int s = 0; s < 2; s++) {
            size_t off = (size_t)(row0 + s * 16 + n) * DIM + qk;
            ah[s] = *(const half8*)(Ah + off);
        }

        float mg = fmaxf(fs.bmG[batch * 128 + lane], fs.bmG[batch * 128 + 64 + lane]);
        float mf = fmaxf(fs.bmF[batch * 128 + lane], fs.bmF[batch * 128 + 64 + lane]);
        #pragma unroll
        for (int m = 1; m < 64; m <<= 1) {
            mg = fmaxf(mg, __shfl_xor(mg, m, 64));
            mf = fmaxf(mf, __shfl_xor(mf, m, 64));
        }
        const float TmaxG = mg;
        const float l2eTG = L2E * mg, l2eTF = L2E * mf;

        // per-lane row weights for the g-side (row = row0 + s*16 + quad*4 + r)
        float vw[2][4];
        #pragma unroll
        for (int s = 0; s < 2; s++)
            #pragma unroll
            for (int r = 0; r < 4; r++)
                vw[s][r] = exp2v(tf[row0 + s * 16 + quad * 4 + r] - l2eTF);

        float sumF[2][4];
        #pragma unroll
        for (int s = 0; s < 2; s++)
            #pragma unroll
            for (int r = 0; r < 4; r++) sumF[s][r] = 0.0f;

        const int c0 = w * CPW + n;
        const u16* bp = Bh + (size_t)c0 * DIM + qk;
        const float* tp = tg + c0;
        float* gpc = fs.gpart + ((size_t)batch * NBLK + blockIdx.x) * NPT + c0;

        half8 b0, b1;
        float t0, t1;
        b0 = *(const half8*)bp;  t0 = *tp;

        auto tile = [&](half8 b, float t, int idx) {
            float wq = exp2v(t - l2eTG);
            floatx4 acc[2];
            #pragma unroll
            for (int s = 0; s < 2; s++) acc[s] = (floatx4){0.f, 0.f, 0.f, 0.f};
            #pragma unroll
            for (int s = 0; s < 2; s++)
                acc[s] = __builtin_amdgcn_mfma_f32_16x16x32_f16(ah[s], b, acc[s], 0, 0, 0);
            float gl = 0.0f;
            #pragma unroll
            for (int s = 0; s < 2; s++)
                #pragma unroll
                for (int r = 0; r < 4; r++) {
                    float e = exp2v(acc[s][r]);
                    sumF[s][r] = fmaf(wq, e, sumF[s][r]);
                    gl = fmaf(vw[s][r], e, gl);
                }
            gl += __shfl_xor(gl, 16, 64);
            gl += __shfl_xor(gl, 32, 64);
            if (lane < 16) gpc[idx * 16] = gl;
        };

        #pragma unroll 1
        for (int ch = 0; ch < NT; ch += 2) {
            b1 = *(const half8*)(bp + (size_t)(ch + 1) * 16 * DIM);
            t1 = tp[(ch + 1) * 16];
            tile(b0, t0, ch);
            if (ch + 2 < NT) {
                b0 = *(const half8*)(bp + (size_t)(ch + 2) * 16 * DIM);
                t0 = tp[(ch + 2) * 16];
            }
            tile(b1, t1, ch + 1);
        }

        #pragma unroll
        for (int s = 0; s < 2; s++)
            #pragma unroll
            for (int r = 0; r < 4; r++) {
                float v = sumF[s][r];
                #pragma unroll
                for (int m = 1; m < 16; m <<= 1) v += __shfl_xor(v, m, 64);
                if (n == 0) lsum[s * 16 + quad * 4 + r][w] = v;
            }
        __syncthreads();

        if (tid < RPB) {
            float T = (lsum[tid][0] + lsum[tid][1]) + (lsum[tid][2] + lsum[tid][3]);
            int l = row0 + tid;
            float lse = TmaxG + __logf(T);
            float val = fs.qX[vbase + l] - lse;
            if (args.average) val = 0.5f * (fs.prevF[vbase + l] + val);
            fs.outF[vbase + l] = val;
            float tc = val + fs.c_x[vbase + l];
            fs.tlsFOut[vbase + l] = L2E * tc;
            float bm = tc;
            #pragma unroll
            for (int m = 1; m < 16; m <<= 1) bm = fmaxf(bm, __shfl_xor(bm, m, 64));
            if ((tid & 15) == 0)
                fs.bmFOut[batch * 128 + blockIdx.x * 2 + (tid >> 4)] = bm;
        }
    } else {
        // ---------------- symmetric sets ----------------
        const SymSet cs = args.s[blockIdx.y - 1];
        const u16* __restrict__ Ah = cs.Ah + pbase;
        const u16* __restrict__ Bh = cs.Bh + pbase;
        const float* __restrict__ tls = cs.tls + vbase;

        half8 ah[2];
        #pragma unroll
        for (int s = 0; s < 2; s++) {
            size_t off = (size_t)(row0 + s * 16 + n) * DIM + qk;
            ah[s] = *(const half8*)(Ah + off);
        }

        float tmv = fmaxf(cs.bmIn[batch * 128 + lane], cs.bmIn[batch * 128 + 64 + lane]);
        #pragma unroll
        for (int m = 1; m < 64; m <<= 1) tmv = fmaxf(tmv, __shfl_xor(tmv, m, 64));
        const float Tmax = tmv;
        const float l2eTmax = L2E * Tmax;

        float sum[2][4];
        #pragma unroll
        for (int s = 0; s < 2; s++)
            #pragma unroll
            for (int r = 0; r < 4; r++) sum[s][r] = 0.0f;

        const int c0 = w * CPW + n;
        const u16* bp = Bh + (size_t)c0 * DIM + qk;
        const float* tp = tls + c0;

        half8 b0, b1;
        float t0, t1;
        b0 = *(const half8*)bp;  t0 = *tp;

        auto tile = [&](half8 b, float t) {
            float bias = t - l2eTmax;
            floatx4 ci = (floatx4){bias, bias, bias, bias};
            floatx4 acc[2];
            #pragma unroll
            for (int s = 0; s < 2; s++)
                acc[s] = __builtin_amdgcn_mfma_f32_16x16x32_f16(ah[s], b, ci, 0, 0, 0);
            #pragma unroll
            for (int s = 0; s < 2; s++)
                #pragma unroll
                for (int r = 0; r < 4; r++)
                    sum[s][r] += exp2v(acc[s][r]);
        };

        #pragma unroll 1
        for (int ch = 0; ch < NT; ch += 2) {
            b1 = *(const half8*)(bp + (size_t)(ch + 1) * 16 * DIM);
            t1 = tp[(ch + 1) * 16];
            tile(b0, t0);
            if (ch + 2 < NT) {
                b0 = *(const half8*)(bp + (size_t)(ch + 2) * 16 * DIM);
                t0 = tp[(ch + 2) * 16];
            }
            tile(b1, t1);
        }

        #pragma unroll
        for (int s = 0; s < 2; s++)
            #pragma unroll
            for (int r = 0; r < 4; r++) {
                float v = sum[s][r];
                #pragma unroll
                for (int m = 1; m < 16; m <<= 1) v += __shfl_xor(v, m, 64);
                if (n == 0) lsum[s * 16 + quad * 4 + r][w] = v;
            }
        __syncthreads();

        if (tid < RPB) {
            float T = (lsum[tid][0] + lsum[tid][1]) + (lsum[tid][2] + lsum[tid][3]);
            int l = row0 + tid;
            float lse = Tmax + __logf(T);
            float val = cs.qX[vbase + l] - lse;
            if (args.average) val = 0.5f * (cs.prev[vbase + l] + val);
            cs.out[vbase + l] = val;
            float tc = val + cs.cwNext[vbase + l];
            cs.tlsOut[vbase + l] = L2E * tc;
            float bm = tc;
            #pragma unroll
            for (int m = 1; m < 16; m <<= 1) bm = fmaxf(bm, __shfl_xor(bm, m, 64));
            if ((tid & 15) == 0)
                cs.bmOut[batch * 128 + blockIdx.x * 2 + (tid >> 4)] = bm;
        }
    }
}

struct GfArgs {
    const float* gpart;   // [BATCH][NBLK][NPT]
    const float* bmF;     // normalization side (rows X of fused pass)
    const float* qY;
    const float* prevG;
    const float* c_y;
    float* outG;
    float* tlsGOut;
    float* bmGOut;
    int average;
};

// Sum the 64 per-block column partials -> gn, tlsG, bmG. 64 blocks x 256 threads.
__global__ __launch_bounds__(256) void gfin_kernel(GfArgs a) {
    const int tid = threadIdx.x;
    const int bx  = blockIdx.x;
    const int batch = bx >> 3;
    const int col = (bx & 7) * 256 + tid;

    __shared__ float sb[128];
    if (tid < 128) sb[tid] = a.bmF[batch * 128 + tid];
    __syncthreads();
    if (tid < 64) {
        float m = fmaxf(sb[tid], sb[tid + 64]);
        #pragma unroll
        for (int k = 1; k < 64; k <<= 1) m = fmaxf(m, __shfl_xor(m, k, 64));
        if (tid == 0) sb[0] = m;
    }
    __syncthreads();
    const float Tmax = sb[0];

    const float* gp = a.gpart + (size_t)batch * NBLK * NPT + col;
    float G = 0.0f;
    #pragma unroll 4
    for (int p = 0; p < NBLK; p++) G += gp[(size_t)p * NPT];

    const size_t idx = (size_t)batch * NPT + col;
    float val = a.qY[idx] - (Tmax + __logf(G));
    if (a.average) val = 0.5f * (a.prevG[idx] + val);
    a.outG[idx] = val;
    float tc = val + a.c_y[idx];
    a.tlsGOut[idx] = L2E * tc;
    float bm = tc;
    #pragma unroll
    for (int m = 1; m < 16; m <<= 1) bm = fmaxf(bm, __shfl_xor(bm, m, 64));
    if ((tid & 15) == 0) a.bmGOut[batch * 128 + (col >> 4)] = bm;
}

struct InitArgs {
    const float *x, *a, *y, *b;
    float *c_x, *c_y, *qx, *qy;
    u16 *xh, *yh, *xsh, *ysh;
    float *f0, *g0, *fx0, *fy0;
    float *tlsF0, *tlsG0, *tlsFx0, *tlsFy0;
    float *bmF0, *bmG0, *bmFx0, *bmFy0;
};

__global__ __launch_bounds__(256) void init_kernel(InitArgs ia) {
    int idx = blockIdx.x * 256 + threadIdx.x;
    if (idx >= BN) return;
    const float* xp = ia.x + (size_t)idx * DIM;
    const float* yp = ia.y + (size_t)idx * DIM;
    u32* xhp  = (u32*)ia.xh  + (size_t)idx * (DIM / 2);
    u32* yhp  = (u32*)ia.yh  + (size_t)idx * (DIM / 2);
    u32* xshp = (u32*)ia.xsh + (size_t)idx * (DIM / 2);
    u32* yshp = (u32*)ia.ysh + (size_t)idx * (DIM / 2);
    float sx = 0.f, sy = 0.f;
    #pragma unroll
    for (int d = 0; d < DIM; d += 2) {
        float v0 = xp[d], v1 = xp[d + 1];
        sx += v0 * v0 + v1 * v1;
        xhp[d / 2]  = (u32)f2h_bits(v0) | ((u32)f2h_bits(v1) << 16);
        xshp[d / 2] = (u32)f2h_bits(L2E * v0) | ((u32)f2h_bits(L2E * v1) << 16);
        float u0 = yp[d], u1 = yp[d + 1];
        sy += u0 * u0 + u1 * u1;
        yhp[d / 2]  = (u32)f2h_bits(u0) | ((u32)f2h_bits(u1) << 16);
        yshp[d / 2] = (u32)f2h_bits(L2E * u0) | ((u32)f2h_bits(L2E * u1) << 16);
    }
    float qxv = 0.5f * sx, qyv = 0.5f * sy;
    ia.qx[idx] = qxv; ia.qy[idx] = qyv;
    float cxv = __logf(ia.a[idx]) - qxv;
    float cyv = __logf(ia.b[idx]) - qyv;
    ia.c_x[idx] = cxv; ia.c_y[idx] = cyv;
    ia.f0[idx] = 0.f; ia.g0[idx] = 0.f; ia.fx0[idx] = 0.f; ia.fy0[idx] = 0.f;
    ia.tlsF0[idx] = L2E * cxv; ia.tlsG0[idx] = L2E * cyv;
    ia.tlsFx0[idx] = L2E * cxv; ia.tlsFy0[idx] = L2E * cyv;
    float mx = cxv, my = cyv;
    #pragma unroll
    for (int m = 1; m < 16; m <<= 1) {
        mx = fmaxf(mx, __shfl_xor(mx, m, 32));
        my = fmaxf(my, __shfl_xor(my, m, 32));
    }
    if ((threadIdx.x & 15) == 0) {
        int g = idx >> 4;
        ia.bmF0[g] = mx; ia.bmFx0[g] = mx;
        ia.bmG0[g] = my; ia.bmFy0[g] = my;
    }
}

__global__ __launch_bounds__(1024) void reduce_kernel(
        const float* __restrict__ a, const float* __restrict__ b,
        const float* __restrict__ ctA, const float* __restrict__ ctB,
        const float* __restrict__ ctX, const float* __restrict__ ctY,
        float* __restrict__ out) {
    float acc = 0.f;
    for (int idx = threadIdx.x; idx < BN; idx += 1024) {
        acc += a[idx] * (ctA[idx] - ctX[idx]) + b[idx] * (ctB[idx] - ctY[idx]);
    }
    #pragma unroll
    for (int off = 32; off > 0; off >>= 1) acc += __shfl_down(acc, off, 64);
    __shared__ float sm[16];
    if ((threadIdx.x & 63) == 0) sm[threadIdx.x >> 6] = acc;
    __syncthreads();
    if (threadIdx.x == 0) {
        float t = 0.f;
        #pragma unroll
        for (int i = 0; i < 16; i++) t += sm[i];
        out[0] = t / (float)BATCH;
    }
}

extern "C" void kernel_launch(void* const* d_in, const int* in_sizes, int n_in,
                              void* d_out, int out_size, void* d_ws, size_t ws_size,
                              hipStream_t stream) {
    const float* x = (const float*)d_in[0];
    const float* a = (const float*)d_in[1];
    const float* y = (const float*)d_in[2];
    const float* b = (const float*)d_in[3];
    float* out = (float*)d_out;

    float* ws = (float*)d_ws;
    float* c_x = ws + 0 * BN;
    float* c_y = ws + 1 * BN;
    float* qx  = ws + 2 * BN;
    float* qy  = ws + 3 * BN;
    float* fb[2]  = { ws + 4 * BN,  ws + 5 * BN };
    float* gb[2]  = { ws + 6 * BN,  ws + 7 * BN };
    float* fxb[2] = { ws + 8 * BN,  ws + 9 * BN };
    float* fyb[2] = { ws + 10 * BN, ws + 11 * BN };
    float* ctA = ws + 12 * BN;
    float* ctB = ws + 13 * BN;
    float* ctX = ws + 14 * BN;
    float* ctY = ws + 15 * BN;
    float* tlsF[2]  = { ws + 16 * BN, ws + 17 * BN };
    float* tlsG[2]  = { ws + 18 * BN, ws + 19 * BN };
    float* tlsFx[2] = { ws + 20 * BN, ws + 21 * BN };
    float* tlsFy[2] = { ws + 22 * BN, ws + 23 * BN };
    float* dummyT = ws + 24 * BN;
    float* small = ws + 25 * BN;
    float* bmF[2]  = { small + 0 * 1024, small + 1 * 1024 };
    float* bmG[2]  = { small + 2 * 1024, small + 3 * 1024 };
    float* bmFx[2] = { small + 4 * 1024, small + 5 * 1024 };
    float* bmFy[2] = { small + 6 * 1024, small + 7 * 1024 };
    float* dummyB = small + 8 * 1024;
    u16* bf = (u16*)(small + 10 * 1024);
    const size_t AS = (size_t)BN * DIM;
    u16* xh  = bf + 0 * AS;
    u16* yh  = bf + 1 * AS;
    u16* xsh = bf + 2 * AS;
    u16* ysh = bf + 3 * AS;
    float* gpart = (float*)(bf + 4 * AS);   // [BATCH][NBLK][NPT] = 4 MB

    InitArgs ia;
    ia.x = x; ia.a = a; ia.y = y; ia.b = b;
    ia.c_x = c_x; ia.c_y = c_y; ia.qx = qx; ia.qy = qy;
    ia.xh = xh; ia.yh = yh; ia.xsh = xsh; ia.ysh = ysh;
    ia.f0 = fb[0]; ia.g0 = gb[0]; ia.fx0 = fxb[0]; ia.fy0 = fyb[0];
    ia.tlsF0 = tlsF[0]; ia.tlsG0 = tlsG[0]; ia.tlsFx0 = tlsFx[0]; ia.tlsFy0 = tlsFy[0];
    ia.bmF0 = bmF[0]; ia.bmG0 = bmG[0]; ia.bmFx0 = bmFx[0]; ia.bmFy0 = bmFy[0];
    init_kernel<<<BN / 256, 256, 0, stream>>>(ia);

    dim3 grid(NBLK, 3, BATCH);
    int cur = 0;
    for (int it = 0; it < 10; it++) {
        CtArgs ar;
        ar.average = 1;
        // fused: fn = ct(g, log_b, kxy) rows X  +  gn partials (ct(f, log_a, kyx))
        ar.fs = { xh, ysh, tlsG[cur], tlsF[cur], qx, bmG[cur], bmF[cur], c_x,
                  fb[cur], fb[1 - cur], tlsF[1 - cur], bmF[1 - cur], gpart };
        // sym x
        ar.s[0] = { xh, xsh, tlsFx[cur], qx, bmFx[cur], c_x,
                    fxb[cur], fxb[1 - cur], tlsFx[1 - cur], bmFx[1 - cur] };
        // sym y
        ar.s[1] = { yh, ysh, tlsFy[cur], qy, bmFy[cur], c_y,
                    fyb[cur], fyb[1 - cur], tlsFy[1 - cur], bmFy[1 - cur] };
        ct2_kernel<<<grid, 256, 0, stream>>>(ar);

        GfArgs ga = { gpart, bmF[cur], qy, gb[cur], c_y,
                      gb[1 - cur], tlsG[1 - cur], bmG[1 - cur], 1 };
        gfin_kernel<<<64, 256, 0, stream>>>(ga);
        cur ^= 1;
    }

    CtArgs fin;
    fin.average = 0;
    fin.fs = { xh, ysh, tlsG[cur], tlsF[cur], qx, bmG[cur], bmF[cur], c_x,
               fb[cur], ctA, dummyT, dummyB, gpart };
    fin.s[0] = { xh, xsh, tlsFx[cur], qx, bmFx[cur], c_x, fxb[cur], ctX, dummyT, dummyB };
    fin.s[1] = { yh, ysh, tlsFy[cur], qy, bmFy[cur], c_y, fyb[cur], ctY, dummyT, dummyB };
    ct2_kernel<<<grid, 256, 0, stream>>>(fin);

    GfArgs gf = { gpart, bmF[cur], qy, gb[cur], c_y, ctB, dummyT, dummyB, 0 };
    gfin_kernel<<<64, 256, 0, stream>>>(gf);

    reduce_kernel<<<1, 1024, 0, stream>>>(a, b, ctA, ctB, ctX, ctY, out);
}

// Round 2
// 324.993 us; speedup vs baseline: 1.2812x; 1.2812x over previous
//
#include <hip/hip_runtime.h>
#include <math.h>

#define BATCH 8
#define NPT   2048
#define DIM   32
#define RPB   64                      // rows per block: 4 strips of 16
#define STRIPS (RPB / 16)
#define NBLKR (NPT / RPB)             // 32 row blocks
#define CPW   (NPT / 4)               // 512 cols per wave
#define NT    (CPW / 16)              // 32 col-tiles of 16 per wave
#define L2E   1.44269504088896f
#define LN2   0.6931471805599453f
#define BN    (BATCH * NPT)

typedef __attribute__((ext_vector_type(8))) _Float16 half8;
typedef __attribute__((ext_vector_type(4))) float floatx4;
typedef unsigned short u16;
typedef unsigned int u32;

__device__ __forceinline__ u16 f2h_bits(float v) {
    _Float16 h = (_Float16)v;
    return *(u16*)&h;
}
__device__ __forceinline__ float exp2v(float x) { return __builtin_amdgcn_exp2f(x); }

struct SymSet {
    const u16* Ah;        // row-side plain fp16 [BATCH][NPT][DIM]
    const u16* Bh;        // col-side log2e-scaled fp16
    const float* tls;     // log2e*(pot+cw) on cols
    const float* qX;      // 0.5*||row||^2
    const float* bmIn;    // [BATCH][128] per-16 max of (pot+cw) on cols
    const float* cwNext;
    const float* prev;
    float* out;
    float* tlsOut;
    float* bmOut;
};
struct FusedSet {
    const u16* Xh;        // rows X plain fp16
    const u16* Ysh;       // cols Y log2e-scaled fp16
    const float* tlsG;    // log2e*(g+c_y) per col  (f-side weights)
    const float* tlsF;    // log2e*(f+c_x) per row  (g-side row bias)
    const float* qX;
    const float* bmG;     // -> TmaxG (normalizes f-side)
    const float* bmF;     // -> TmaxF (normalizes g-side)
    const float* c_x;
    const float* prevF;
    float* outF;
    float* tlsFOut;
    float* bmFOut;
    float* gpart;         // [BATCH][NBLKR][NPT] row-weighted col partials
};
struct CtArgs { FusedSet fs; SymSet s[2]; int average; };

// blockIdx.y==0: fused pass over kxy producing f-row LSE AND g-col partials.
//   acc = L2E*x.y + (tf_l - L2E*TmaxF)   (row bias in MFMA C-operand)
//   e' = 2^acc; gl += e' (row-weighted, exactly set1's terms);
//   sumF += 2^(tg_k - L2E*TmaxG) * e'; row factor divided out in finalize.
// blockIdx.y==1,2: symmetric sets, col bias folded into MFMA C-operand.
__global__ __launch_bounds__(256, 3) void ct2_kernel(CtArgs args) {
    const int batch = blockIdx.z;
    const int row0 = blockIdx.x * RPB;
    const int tid  = threadIdx.x;
    const int w = tid >> 6, lane = tid & 63, n = lane & 15, quad = lane >> 4;
    const int qk = quad * 8;
    const size_t pbase = (size_t)batch * NPT * DIM;
    const size_t vbase = (size_t)batch * NPT;

    __shared__ float lsum[RPB][4];

    if (blockIdx.y == 0) {
        // ---------------- fused cross pass ----------------
        const FusedSet fs = args.fs;
        const u16* __restrict__ Ah = fs.Xh + pbase;
        const u16* __restrict__ Bh = fs.Ysh + pbase;
        const float* __restrict__ tg = fs.tlsG + vbase;
        const float* __restrict__ tf = fs.tlsF + vbase;

        half8 ah[STRIPS];
        #pragma unroll
        for (int s = 0; s < STRIPS; s++) {
            size_t off = (size_t)(row0 + s * 16 + n) * DIM + qk;
            ah[s] = *(const half8*)(Ah + off);
        }

        float mg = fmaxf(fs.bmG[batch * 128 + lane], fs.bmG[batch * 128 + 64 + lane]);
        float mf = fmaxf(fs.bmF[batch * 128 + lane], fs.bmF[batch * 128 + 64 + lane]);
        #pragma unroll
        for (int m = 1; m < 64; m <<= 1) {
            mg = fmaxf(mg, __shfl_xor(mg, m, 64));
            mf = fmaxf(mf, __shfl_xor(mf, m, 64));
        }
        const float TmaxG = mg;
        const float l2eTG = L2E * mg, l2eTF = L2E * mf;

        // row-bias C operands (per block constant)
        floatx4 cis[STRIPS];
        #pragma unroll
        for (int s = 0; s < STRIPS; s++)
            #pragma unroll
            for (int r = 0; r < 4; r++)
                cis[s][r] = tf[row0 + s * 16 + quad * 4 + r] - l2eTF;

        float sumF[STRIPS][4];
        #pragma unroll
        for (int s = 0; s < STRIPS; s++)
            #pragma unroll
            for (int r = 0; r < 4; r++) sumF[s][r] = 0.0f;

        const int c0 = w * CPW + n;
        const u16* bp = Bh + (size_t)c0 * DIM + qk;
        const float* tp = tg + c0;
        float* gpc = fs.gpart + ((size_t)batch * NBLKR + blockIdx.x) * NPT + c0;

        half8 bb[4];
        float tt[4];
        bb[0] = *(const half8*)bp;                       tt[0] = tp[0];
        bb[1] = *(const half8*)(bp + (size_t)16 * DIM);  tt[1] = tp[16];

        auto tile = [&](half8 b, float t, int idx) {
            float wq = exp2v(t - l2eTG);
            floatx4 acc[STRIPS];
            #pragma unroll
            for (int s = 0; s < STRIPS; s++)
                acc[s] = __builtin_amdgcn_mfma_f32_16x16x32_f16(ah[s], b, cis[s], 0, 0, 0);
            float gl = 0.0f;
            #pragma unroll
            for (int s = 0; s < STRIPS; s++)
                #pragma unroll
                for (int r = 0; r < 4; r++) {
                    float e = exp2v(acc[s][r]);
                    sumF[s][r] = fmaf(wq, e, sumF[s][r]);
                    gl += e;
                }
            gl += __shfl_xor(gl, 16, 64);
            gl += __shfl_xor(gl, 32, 64);
            if (lane < 16) gpc[idx * 16] = gl;
        };

        #pragma unroll 1
        for (int ch = 0; ch < NT; ch += 4) {
            #pragma unroll
            for (int j = 0; j < 4; j++) {
                int nx = ch + j + 2;
                int nxc = nx < NT ? nx : NT - 1;          // clamped, branch-free
                bb[(j + 2) & 3] = *(const half8*)(bp + (size_t)nxc * 16 * DIM);
                tt[(j + 2) & 3] = tp[nxc * 16];
                tile(bb[j], tt[j], ch + j);
            }
        }

        #pragma unroll
        for (int s = 0; s < STRIPS; s++)
            #pragma unroll
            for (int r = 0; r < 4; r++) {
                float v = sumF[s][r];
                #pragma unroll
                for (int m = 1; m < 16; m <<= 1) v += __shfl_xor(v, m, 64);
                if (n == 0) lsum[s * 16 + quad * 4 + r][w] = v;
            }
        __syncthreads();

        if (tid < RPB) {
            float T = (lsum[tid][0] + lsum[tid][1]) + (lsum[tid][2] + lsum[tid][3]);
            int l = row0 + tid;
            // divide out the row factor 2^(tf_l - l2eTF)
            float lse = TmaxG + __logf(T) - LN2 * (tf[l] - l2eTF);
            float val = fs.qX[vbase + l] - lse;
            if (args.average) val = 0.5f * (fs.prevF[vbase + l] + val);
            fs.outF[vbase + l] = val;
            float tc = val + fs.c_x[vbase + l];
            fs.tlsFOut[vbase + l] = L2E * tc;
            float bm = tc;
            #pragma unroll
            for (int m = 1; m < 16; m <<= 1) bm = fmaxf(bm, __shfl_xor(bm, m, 64));
            if ((tid & 15) == 0)
                fs.bmFOut[batch * 128 + blockIdx.x * STRIPS + (tid >> 4)] = bm;
        }
    } else {
        // ---------------- symmetric sets ----------------
        const SymSet cs = args.s[blockIdx.y - 1];
        const u16* __restrict__ Ah = cs.Ah + pbase;
        const u16* __restrict__ Bh = cs.Bh + pbase;
        const float* __restrict__ tls = cs.tls + vbase;

        half8 ah[STRIPS];
        #pragma unroll
        for (int s = 0; s < STRIPS; s++) {
            size_t off = (size_t)(row0 + s * 16 + n) * DIM + qk;
            ah[s] = *(const half8*)(Ah + off);
        }

        float tmv = fmaxf(cs.bmIn[batch * 128 + lane], cs.bmIn[batch * 128 + 64 + lane]);
        #pragma unroll
        for (int m = 1; m < 64; m <<= 1) tmv = fmaxf(tmv, __shfl_xor(tmv, m, 64));
        const float Tmax = tmv;
        const float l2eTmax = L2E * Tmax;

        float sum[STRIPS][4];
        #pragma unroll
        for (int s = 0; s < STRIPS; s++)
            #pragma unroll
            for (int r = 0; r < 4; r++) sum[s][r] = 0.0f;

        const int c0 = w * CPW + n;
        const u16* bp = Bh + (size_t)c0 * DIM + qk;
        const float* tp = tls + c0;

        half8 bb[4];
        float tt[4];
        bb[0] = *(const half8*)bp;                       tt[0] = tp[0];
        bb[1] = *(const half8*)(bp + (size_t)16 * DIM);  tt[1] = tp[16];

        auto tile = [&](half8 b, float t) {
            float bias = t - l2eTmax;
            floatx4 ci = (floatx4){bias, bias, bias, bias};
            floatx4 acc[STRIPS];
            #pragma unroll
            for (int s = 0; s < STRIPS; s++)
                acc[s] = __builtin_amdgcn_mfma_f32_16x16x32_f16(ah[s], b, ci, 0, 0, 0);
            #pragma unroll
            for (int s = 0; s < STRIPS; s++)
                #pragma unroll
                for (int r = 0; r < 4; r++)
                    sum[s][r] += exp2v(acc[s][r]);
        };

        #pragma unroll 1
        for (int ch = 0; ch < NT; ch += 4) {
            #pragma unroll
            for (int j = 0; j < 4; j++) {
                int nx = ch + j + 2;
                int nxc = nx < NT ? nx : NT - 1;
                bb[(j + 2) & 3] = *(const half8*)(bp + (size_t)nxc * 16 * DIM);
                tt[(j + 2) & 3] = tp[nxc * 16];
                tile(bb[j], tt[j]);
            }
        }

        #pragma unroll
        for (int s = 0; s < STRIPS; s++)
            #pragma unroll
            for (int r = 0; r < 4; r++) {
                float v = sum[s][r];
                #pragma unroll
                for (int m = 1; m < 16; m <<= 1) v += __shfl_xor(v, m, 64);
                if (n == 0) lsum[s * 16 + quad * 4 + r][w] = v;
            }
        __syncthreads();

        if (tid < RPB) {
            float T = (lsum[tid][0] + lsum[tid][1]) + (lsum[tid][2] + lsum[tid][3]);
            int l = row0 + tid;
            float lse = Tmax + __logf(T);
            float val = cs.qX[vbase + l] - lse;
            if (args.average) val = 0.5f * (cs.prev[vbase + l] + val);
            cs.out[vbase + l] = val;
            float tc = val + cs.cwNext[vbase + l];
            cs.tlsOut[vbase + l] = L2E * tc;
            float bm = tc;
            #pragma unroll
            for (int m = 1; m < 16; m <<= 1) bm = fmaxf(bm, __shfl_xor(bm, m, 64));
            if ((tid & 15) == 0)
                cs.bmOut[batch * 128 + blockIdx.x * STRIPS + (tid >> 4)] = bm;
        }
    }
}

struct GfArgs {
    const float* gpart;   // [BATCH][NBLKR][NPT]
    const float* bmF;
    const float* qY;
    const float* prevG;
    const float* c_y;
    float* outG;
    float* tlsGOut;
    float* bmGOut;
    int average;
};

// Sum 32 per-row-block column partials -> gn, tlsG, bmG.
// 256 blocks (8 batch x 32 col-chunks of 64), 4-way p-split per block.
__global__ __launch_bounds__(256) void gfin_kernel(GfArgs a) {
    const int tid = threadIdx.x;
    const int batch = blockIdx.x >> 5;
    const int chunk = blockIdx.x & 31;
    const int g = tid >> 6, c = tid & 63;
    const int col = chunk * 64 + c;

    __shared__ float sb[128];
    __shared__ float ps[4][64];
    if (tid < 128) sb[tid] = a.bmF[batch * 128 + tid];
    __syncthreads();

    // every wave reduces the same 128 values -> all threads hold Tmax
    float m = fmaxf(sb[tid & 63], sb[(tid & 63) + 64]);
    #pragma unroll
    for (int k = 1; k < 64; k <<= 1) m = fmaxf(m, __shfl_xor(m, k, 64));
    const float Tmax = m;

    const float* gp = a.gpart + ((size_t)batch * NBLKR + g) * NPT + col;
    float G = 0.0f;
    #pragma unroll
    for (int p = 0; p < NBLKR / 4; p++) G += gp[(size_t)p * 4 * NPT];
    ps[g][c] = G;
    __syncthreads();

    if (tid < 64) {
        float Gt = (ps[0][tid] + ps[1][tid]) + (ps[2][tid] + ps[3][tid]);
        const int colT = chunk * 64 + tid;
        const size_t idx = (size_t)batch * NPT + colT;
        float val = a.qY[idx] - (Tmax + __logf(Gt));
        if (a.average) val = 0.5f * (a.prevG[idx] + val);
        a.outG[idx] = val;
        float tc = val + a.c_y[idx];
        a.tlsGOut[idx] = L2E * tc;
        float bm = tc;
        #pragma unroll
        for (int k = 1; k < 16; k <<= 1) bm = fmaxf(bm, __shfl_xor(bm, k, 64));
        if ((tid & 15) == 0) a.bmGOut[batch * 128 + (colT >> 4)] = bm;
    }
}

struct InitArgs {
    const float *x, *a, *y, *b;
    float *c_x, *c_y, *qx, *qy;
    u16 *xh, *yh, *xsh, *ysh;
    float *f0, *g0, *fx0, *fy0;
    float *tlsF0, *tlsG0, *tlsFx0, *tlsFy0;
    float *bmF0, *bmG0, *bmFx0, *bmFy0;
};

__global__ __launch_bounds__(256) void init_kernel(InitArgs ia) {
    int idx = blockIdx.x * 256 + threadIdx.x;
    if (idx >= BN) return;
    const float* xp = ia.x + (size_t)idx * DIM;
    const float* yp = ia.y + (size_t)idx * DIM;
    u32* xhp  = (u32*)ia.xh  + (size_t)idx * (DIM / 2);
    u32* yhp  = (u32*)ia.yh  + (size_t)idx * (DIM / 2);
    u32* xshp = (u32*)ia.xsh + (size_t)idx * (DIM / 2);
    u32* yshp = (u32*)ia.ysh + (size_t)idx * (DIM / 2);
    float sx = 0.f, sy = 0.f;
    #pragma unroll
    for (int d = 0; d < DIM; d += 2) {
        float v0 = xp[d], v1 = xp[d + 1];
        sx += v0 * v0 + v1 * v1;
        xhp[d / 2]  = (u32)f2h_bits(v0) | ((u32)f2h_bits(v1) << 16);
        xshp[d / 2] = (u32)f2h_bits(L2E * v0) | ((u32)f2h_bits(L2E * v1) << 16);
        float u0 = yp[d], u1 = yp[d + 1];
        sy += u0 * u0 + u1 * u1;
        yhp[d / 2]  = (u32)f2h_bits(u0) | ((u32)f2h_bits(u1) << 16);
        yshp[d / 2] = (u32)f2h_bits(L2E * u0) | ((u32)f2h_bits(L2E * u1) << 16);
    }
    float qxv = 0.5f * sx, qyv = 0.5f * sy;
    ia.qx[idx] = qxv; ia.qy[idx] = qyv;
    float cxv = __logf(ia.a[idx]) - qxv;
    float cyv = __logf(ia.b[idx]) - qyv;
    ia.c_x[idx] = cxv; ia.c_y[idx] = cyv;
    ia.f0[idx] = 0.f; ia.g0[idx] = 0.f; ia.fx0[idx] = 0.f; ia.fy0[idx] = 0.f;
    ia.tlsF0[idx] = L2E * cxv; ia.tlsG0[idx] = L2E * cyv;
    ia.tlsFx0[idx] = L2E * cxv; ia.tlsFy0[idx] = L2E * cyv;
    float mx = cxv, my = cyv;
    #pragma unroll
    for (int m = 1; m < 16; m <<= 1) {
        mx = fmaxf(mx, __shfl_xor(mx, m, 32));
        my = fmaxf(my, __shfl_xor(my, m, 32));
    }
    if ((threadIdx.x & 15) == 0) {
        int g = idx >> 4;
        ia.bmF0[g] = mx; ia.bmFx0[g] = mx;
        ia.bmG0[g] = my; ia.bmFy0[g] = my;
    }
}

__global__ __launch_bounds__(1024) void reduce_kernel(
        const float* __restrict__ a, const float* __restrict__ b,
        const float* __restrict__ ctA, const float* __restrict__ ctB,
        const float* __restrict__ ctX, const float* __restrict__ ctY,
        float* __restrict__ out) {
    float acc = 0.f;
    for (int idx = threadIdx.x; idx < BN; idx += 1024) {
        acc += a[idx] * (ctA[idx] - ctX[idx]) + b[idx] * (ctB[idx] - ctY[idx]);
    }
    #pragma unroll
    for (int off = 32; off > 0; off >>= 1) acc += __shfl_down(acc, off, 64);
    __shared__ float sm[16];
    if ((threadIdx.x & 63) == 0) sm[threadIdx.x >> 6] = acc;
    __syncthreads();
    if (threadIdx.x == 0) {
        float t = 0.f;
        #pragma unroll
        for (int i = 0; i < 16; i++) t += sm[i];
        out[0] = t / (float)BATCH;
    }
}

extern "C" void kernel_launch(void* const* d_in, const int* in_sizes, int n_in,
                              void* d_out, int out_size, void* d_ws, size_t ws_size,
                              hipStream_t stream) {
    const float* x = (const float*)d_in[0];
    const float* a = (const float*)d_in[1];
    const float* y = (const float*)d_in[2];
    const float* b = (const float*)d_in[3];
    float* out = (float*)d_out;

    float* ws = (float*)d_ws;
    float* c_x = ws + 0 * BN;
    float* c_y = ws + 1 * BN;
    float* qx  = ws + 2 * BN;
    float* qy  = ws + 3 * BN;
    float* fb[2]  = { ws + 4 * BN,  ws + 5 * BN };
    float* gb[2]  = { ws + 6 * BN,  ws + 7 * BN };
    float* fxb[2] = { ws + 8 * BN,  ws + 9 * BN };
    float* fyb[2] = { ws + 10 * BN, ws + 11 * BN };
    float* ctA = ws + 12 * BN;
    float* ctB = ws + 13 * BN;
    float* ctX = ws + 14 * BN;
    float* ctY = ws + 15 * BN;
    float* tlsF[2]  = { ws + 16 * BN, ws + 17 * BN };
    float* tlsG[2]  = { ws + 18 * BN, ws + 19 * BN };
    float* tlsFx[2] = { ws + 20 * BN, ws + 21 * BN };
    float* tlsFy[2] = { ws + 22 * BN, ws + 23 * BN };
    float* dummyT = ws + 24 * BN;
    float* small = ws + 25 * BN;
    float* bmF[2]  = { small + 0 * 1024, small + 1 * 1024 };
    float* bmG[2]  = { small + 2 * 1024, small + 3 * 1024 };
    float* bmFx[2] = { small + 4 * 1024, small + 5 * 1024 };
    float* bmFy[2] = { small + 6 * 1024, small + 7 * 1024 };
    float* dummyB = small + 8 * 1024;
    u16* bf = (u16*)(small + 10 * 1024);
    const size_t AS = (size_t)BN * DIM;
    u16* xh  = bf + 0 * AS;
    u16* yh  = bf + 1 * AS;
    u16* xsh = bf + 2 * AS;
    u16* ysh = bf + 3 * AS;
    float* gpart = (float*)(bf + 4 * AS);   // [BATCH][NBLKR][NPT] = 2 MB

    InitArgs ia;
    ia.x = x; ia.a = a; ia.y = y; ia.b = b;
    ia.c_x = c_x; ia.c_y = c_y; ia.qx = qx; ia.qy = qy;
    ia.xh = xh; ia.yh = yh; ia.xsh = xsh; ia.ysh = ysh;
    ia.f0 = fb[0]; ia.g0 = gb[0]; ia.fx0 = fxb[0]; ia.fy0 = fyb[0];
    ia.tlsF0 = tlsF[0]; ia.tlsG0 = tlsG[0]; ia.tlsFx0 = tlsFx[0]; ia.tlsFy0 = tlsFy[0];
    ia.bmF0 = bmF[0]; ia.bmG0 = bmG[0]; ia.bmFx0 = bmFx[0]; ia.bmFy0 = bmFy[0];
    init_kernel<<<BN / 256, 256, 0, stream>>>(ia);

    dim3 grid(NBLKR, 3, BATCH);
    int cur = 0;
    for (int it = 0; it < 10; it++) {
        CtArgs ar;
        ar.average = 1;
        // fused: fn = ct(g, log_b, kxy) rows X  +  gn partials (ct(f, log_a, kyx))
        ar.fs = { xh, ysh, tlsG[cur], tlsF[cur], qx, bmG[cur], bmF[cur], c_x,
                  fb[cur], fb[1 - cur], tlsF[1 - cur], bmF[1 - cur], gpart };
        // sym x
        ar.s[0] = { xh, xsh, tlsFx[cur], qx, bmFx[cur], c_x,
                    fxb[cur], fxb[1 - cur], tlsFx[1 - cur], bmFx[1 - cur] };
        // sym y
        ar.s[1] = { yh, ysh, tlsFy[cur], qy, bmFy[cur], c_y,
                    fyb[cur], fyb[1 - cur], tlsFy[1 - cur], bmFy[1 - cur] };
        ct2_kernel<<<grid, 256, 0, stream>>>(ar);

        GfArgs ga = { gpart, bmF[cur], qy, gb[cur], c_y,
                      gb[1 - cur], tlsG[1 - cur], bmG[1 - cur], 1 };
        gfin_kernel<<<256, 256, 0, stream>>>(ga);
        cur ^= 1;
    }

    CtArgs fin;
    fin.average = 0;
    fin.fs = { xh, ysh, tlsG[cur], tlsF[cur], qx, bmG[cur], bmF[cur], c_x,
               fb[cur], ctA, dummyT, dummyB, gpart };
    fin.s[0] = { xh, xsh, tlsFx[cur], qx, bmFx[cur], c_x, fxb[cur], ctX, dummyT, dummyB };
    fin.s[1] = { yh, ysh, tlsFy[cur], qy, bmFy[cur], c_y, fyb[cur], ctY, dummyT, dummyB };
    ct2_kernel<<<grid, 256, 0, stream>>>(fin);

    GfArgs gf = { gpart, bmF[cur], qy, gb[cur], c_y, ctB, dummyT, dummyB, 0 };
    gfin_kernel<<<256, 256, 0, stream>>>(gf);

    reduce_kernel<<<1, 1024, 0, stream>>>(a, b, ctA, ctB, ctX, ctY, out);
}